// Round 14
// baseline (1752.315 us; speedup 1.0000x reference)
//
#include <hip/hip_runtime.h>

#define NN 100000
#define NE 1600000
#define DI 128
#define DH 128
#define DO 64
#define NN16 ((size_t)NN * 16)
#define NBK 391           // buckets of 256 nodes (dst >> 8)
#define SLOT 5120         // per-bucket slot capacity
#define PAD 16            // one counter per 64B line
#define EPB 8192          // edges per scatter block
#define NSB ((NE + EPB - 1) / EPB)  // 196

typedef unsigned int uint;
typedef unsigned short ushort;
typedef __bf16 bf16x8 __attribute__((ext_vector_type(8)));
typedef float f32x4 __attribute__((ext_vector_type(4)));

// ---- bf16 helpers (manual, RTNE) ----
__device__ __forceinline__ float bf_lo(uint u) { return __uint_as_float(u << 16); }
__device__ __forceinline__ float bf_hi(uint u) { return __uint_as_float(u & 0xffff0000u); }
__device__ __forceinline__ ushort f2bf(float f) {
    uint u = __float_as_uint(f);
    uint r = u + 0x7fffu + ((u >> 16) & 1u);
    return (ushort)(r >> 16);
}

// ---- prep: bucket cursor init + weight transposes ----
__global__ void k_prep(const float* __restrict__ W1, const float* __restrict__ W2,
                       ushort* __restrict__ w1t, ushort* __restrict__ w2t,
                       int* __restrict__ bcur) {
    int t = blockIdx.x * 256 + threadIdx.x;
    if (t < NBK) bcur[t * PAD] = t * SLOT;
    if (t < 128 * 128) {
        int c = t >> 7, k = t & 127;
        w1t[t] = f2bf(W1[k * 128 + c]);
    } else if (t < 128 * 128 + 64 * 128) {
        int u = t - 128 * 128;
        int c = u >> 7, k = u & 127;
        w2t[u] = f2bf(W2[k * 64 + c]);
    }
}

// ---- staged bucket scatter: LDS counting sort per 8192-edge block ----
// emits ebuf[p] = (src<<8) | (dst&255), grouped into per-bucket slot regions
__global__ __launch_bounds__(512) void k_bscatter(const int* __restrict__ src,
                                                  const int* __restrict__ dst,
                                                  int* __restrict__ bcur,
                                                  uint* __restrict__ ebuf) {
    __shared__ uint stage[EPB];        // 32 KB
    __shared__ ushort bktid[EPB];      // 16 KB
    __shared__ int lcnt[NBK];
    __shared__ int loff[NBK];
    __shared__ int gbase[NBK];
    __shared__ int s[512];
    int t = threadIdx.x;
    int e0 = blockIdx.x * EPB;
    int n = min(EPB, NE - e0);
    for (int i = t; i < NBK; i += 512) lcnt[i] = 0;
    __syncthreads();
    for (int i = t; i < n; i += 512)
        atomicAdd(&lcnt[dst[e0 + i] >> 8], 1);
    __syncthreads();
    int myc = (t < NBK) ? lcnt[t] : 0;
    s[t] = myc;
    __syncthreads();
    for (int d = 1; d < 512; d <<= 1) {
        int a = (t >= d) ? s[t - d] : 0;
        __syncthreads();
        s[t] += a;
        __syncthreads();
    }
    if (t < NBK) {
        loff[t] = s[t] - myc;
        gbase[t] = atomicAdd(&bcur[t * PAD], myc);
        lcnt[t] = s[t] - myc;
    }
    __syncthreads();
    for (int i = t; i < n; i += 512) {
        int d = dst[e0 + i];
        int sv = src[e0 + i];
        int b = d >> 8;
        int p = atomicAdd(&lcnt[b], 1);
        stage[p] = ((uint)sv << 8) | (uint)(d & 255);
        bktid[p] = (ushort)b;
    }
    __syncthreads();
    for (int j = t; j < n; j += 512) {
        int b = bktid[j];
        ebuf[gbase[b] + (j - loff[b])] = stage[j];
    }
}

// ---- per-bucket degree histogram -> inv (no CSR fill needed anymore) ----
__global__ __launch_bounds__(256) void k_deginv(const uint* __restrict__ ebuf,
                                                const int* __restrict__ bcur,
                                                float* __restrict__ inv) {
    __shared__ int cnt[256];
    int b = blockIdx.x, t = threadIdx.x;
    cnt[t] = 0;
    __syncthreads();
    int ebeg = b * SLOT;
    int eend = bcur[b * PAD];
    for (int e = ebeg + t; e < eend; e += 256)
        atomicAdd(&cnt[ebuf[e] & 255], 1);
    __syncthreads();
    int node = b * 256 + t;
    if (node < NN) inv[node] = rsqrtf((float)cnt[t] + 1.0f);
}

// ---------------- MFMA GEMM: one wave = 32 rows x N cols, K=128 ----------------
// A: fp32 row-major (ABF16=false) or bf16 slice-major [8][NN][16] (ABF16=true)
// out: bf16 slice-major [N/16][NN][16], row r scaled by inv[r]
template <int N, bool ABF16>
__global__ __launch_bounds__(256) void k_gemm_mfma(const void* __restrict__ Ap,
                                                   const ushort* __restrict__ Wt,
                                                   const float* __restrict__ inv,
                                                   ushort* __restrict__ out) {
    int wid = threadIdx.x >> 6;
    int lane = threadIdx.x & 63;
    int r0 = (blockIdx.x * 4 + wid) * 32;
    if (r0 >= NN) return;
    int rlo = lane & 15, khi = lane >> 4;  // khi in 0..3

    constexpr int CT = N / 16;  // 8 (N=128) or 4 (N=64)
    f32x4 acc[2][CT] = {};

#pragma unroll
    for (int ks = 0; ks < 4; ++ks) {
        bf16x8 bf[CT];
#pragma unroll
        for (int ct = 0; ct < CT; ++ct)
            bf[ct] = *(const bf16x8*)(Wt + (ct * 16 + rlo) * 128 + ks * 32 + khi * 8);
#pragma unroll
        for (int rt = 0; rt < 2; ++rt) {
            int row = r0 + rt * 16 + rlo;
            bf16x8 af;
            if (ABF16) {
                const ushort* As = (const ushort*)Ap;
                af = *(const bf16x8*)(As + (size_t)(2 * ks + (khi >> 1)) * NN16 +
                                      (size_t)row * 16 + (khi & 1) * 8);
            } else {
                const float* pa = (const float*)Ap + (size_t)row * 128 + ks * 32 + khi * 8;
                float4 f0 = *(const float4*)pa;
                float4 f1 = *(const float4*)(pa + 4);
                af[0] = (__bf16)f0.x; af[1] = (__bf16)f0.y;
                af[2] = (__bf16)f0.z; af[3] = (__bf16)f0.w;
                af[4] = (__bf16)f1.x; af[5] = (__bf16)f1.y;
                af[6] = (__bf16)f1.z; af[7] = (__bf16)f1.w;
            }
#pragma unroll
            for (int ct = 0; ct < CT; ++ct)
                acc[rt][ct] = __builtin_amdgcn_mfma_f32_16x16x32_bf16(af, bf[ct], acc[rt][ct], 0, 0, 0);
        }
    }
#pragma unroll
    for (int rt = 0; rt < 2; ++rt) {
        int rowb = r0 + rt * 16 + 4 * khi;
#pragma unroll
        for (int b = 0; b < 4; ++b) {
            float sc = inv[rowb + b];
#pragma unroll
            for (int ct = 0; ct < CT; ++ct)
                out[(size_t)ct * NN16 + (size_t)(rowb + b) * 16 + rlo] = f2bf(acc[rt][ct][b] * sc);
        }
    }
}

// ---- accumulate one 16-feat table row into LDS accumulator a[0..15] ----
#define LACC(L, H, a)                                                     \
    do {                                                                  \
        atomicAdd((a) + 0, bf_lo((L).x));  atomicAdd((a) + 1, bf_hi((L).x));  \
        atomicAdd((a) + 2, bf_lo((L).y));  atomicAdd((a) + 3, bf_hi((L).y));  \
        atomicAdd((a) + 4, bf_lo((L).z));  atomicAdd((a) + 5, bf_hi((L).z));  \
        atomicAdd((a) + 6, bf_lo((L).w));  atomicAdd((a) + 7, bf_hi((L).w));  \
        atomicAdd((a) + 8, bf_lo((H).x));  atomicAdd((a) + 9, bf_hi((H).x));  \
        atomicAdd((a) + 10, bf_lo((H).y)); atomicAdd((a) + 11, bf_hi((H).y)); \
        atomicAdd((a) + 12, bf_lo((H).z)); atomicAdd((a) + 13, bf_hi((H).z)); \
        atomicAdd((a) + 14, bf_lo((H).w)); atomicAdd((a) + 15, bf_hi((H).w)); \
    } while (0)

// ---------------- edge-parallel sliced aggregation with LDS accumulators ----------------
// block = bucket (256 dst nodes) x 16-feat slice; tab sliced [NS][NN][16] (inv-scaled).
// Each thread streams edges (coalesced ebuf), gathers the src row (32B, L2-resident
// slice via XCD pinning slice=blockIdx&(NS-1)), accumulates via ds_add_f32.
template <int NS, bool RELU, bool F32OUT>
__global__ __launch_bounds__(256) void k_aggl(const uint* __restrict__ ebuf,
                                              const int* __restrict__ bcur,
                                              const ushort* __restrict__ tab,
                                              const float* __restrict__ inv,
                                              const float* __restrict__ bias,
                                              void* __restrict__ outp) {
    __shared__ float acc[256 * 17];  // stride 17 dwords -> bank-spread
    int slice = blockIdx.x & (NS - 1);
    int b = blockIdx.x / NS;
    int t = threadIdx.x;
#pragma unroll
    for (int i = 0; i < 17; ++i) acc[i * 256 + t] = 0.f;
    __syncthreads();
    const uint4* t128 = (const uint4*)((const uint*)tab + (size_t)slice * (NN * 8));
    int ebeg = b * SLOT;
    int eend = bcur[b * PAD];
    int e = ebeg + t;
    for (; e + 256 < eend; e += 512) {
        uint ed0 = ebuf[e];
        uint ed1 = ebuf[e + 256];
        int s0 = (int)(ed0 >> 8), d0 = (int)(ed0 & 255);
        int s1 = (int)(ed1 >> 8), d1 = (int)(ed1 & 255);
        uint4 l0 = t128[(size_t)s0 * 2], h0 = t128[(size_t)s0 * 2 + 1];
        uint4 l1 = t128[(size_t)s1 * 2], h1 = t128[(size_t)s1 * 2 + 1];
        float* a0 = acc + d0 * 17;
        float* a1 = acc + d1 * 17;
        LACC(l0, h0, a0);
        LACC(l1, h1, a1);
    }
    if (e < eend) {
        uint ed0 = ebuf[e];
        int s0 = (int)(ed0 >> 8), d0 = (int)(ed0 & 255);
        uint4 l0 = t128[(size_t)s0 * 2], h0 = t128[(size_t)s0 * 2 + 1];
        float* a0 = acc + d0 * 17;
        LACC(l0, h0, a0);
    }
    __syncthreads();
    // epilogue: thread t owns node b*256+t
    int node = b * 256 + t;
    if (node >= NN) return;
    float invd = inv[node];
    uint4 sl = t128[(size_t)node * 2], sh = t128[(size_t)node * 2 + 1];
    float sf[16];
    sf[0] = bf_lo(sl.x);  sf[1] = bf_hi(sl.x);
    sf[2] = bf_lo(sl.y);  sf[3] = bf_hi(sl.y);
    sf[4] = bf_lo(sl.z);  sf[5] = bf_hi(sl.z);
    sf[6] = bf_lo(sl.w);  sf[7] = bf_hi(sl.w);
    sf[8] = bf_lo(sh.x);  sf[9] = bf_hi(sh.x);
    sf[10] = bf_lo(sh.y); sf[11] = bf_hi(sh.y);
    sf[12] = bf_lo(sh.z); sf[13] = bf_hi(sh.z);
    sf[14] = bf_lo(sh.w); sf[15] = bf_hi(sh.w);
    const float* bb = bias + slice * 16;
    float* a = acc + t * 17;
    float r[16];
#pragma unroll
    for (int f = 0; f < 16; ++f) {
        r[f] = fmaf(invd, a[f] + sf[f], bb[f]);
        if (RELU) r[f] = fmaxf(r[f], 0.f);
    }
    if (F32OUT) {
        float* out = (float*)outp + (size_t)node * 64 + slice * 16;
#pragma unroll
        for (int q = 0; q < 4; ++q)
            *(float4*)(out + q * 4) = make_float4(r[q * 4], r[q * 4 + 1], r[q * 4 + 2], r[q * 4 + 3]);
    } else {
        uint o[8];
#pragma unroll
        for (int q = 0; q < 8; ++q)
            o[q] = (uint)f2bf(r[q * 2]) | ((uint)f2bf(r[q * 2 + 1]) << 16);
        uint* ob = (uint*)outp + (size_t)slice * (NN * 8) + (size_t)node * 8;
        *(uint4*)ob = make_uint4(o[0], o[1], o[2], o[3]);
        *(uint4*)(ob + 4) = make_uint4(o[4], o[5], o[6], o[7]);
    }
}

extern "C" void kernel_launch(void* const* d_in, const int* in_sizes, int n_in,
                              void* d_out, int out_size, void* d_ws, size_t ws_size,
                              hipStream_t stream) {
    const float* x  = (const float*)d_in[0];
    const int* ei   = (const int*)d_in[1];
    const int* src  = ei;        // edge_index[0]
    const int* dst  = ei + NE;   // edge_index[1]
    const float* W1 = (const float*)d_in[2];
    const float* b1 = (const float*)d_in[3];
    const float* W2 = (const float*)d_in[4];
    const float* b2 = (const float*)d_in[5];
    float* out = (float*)d_out;

    // workspace layout (16B alignment maintained)
    float*  inv     = (float*)d_ws;                      // 100004 floats
    int*    bcur    = (int*)(inv + 100004);              // NBK*16 ints (padded)
    uint*   ebuf    = (uint*)(bcur + NBK * PAD);         // NBK*SLOT uints (persists whole run)
    ushort* w1t     = (ushort*)(ebuf + NBK * SLOT);      // 128*128 bf16
    ushort* w2t     = w1t + 128 * 128;                   // 64*128 bf16
    ushort* h       = w2t + 64 * 128;                    // [8][NN][16] bf16 (inv-scaled)
    ushort* hagg    = h + (size_t)NN * DH;               // [8][NN][16] bf16
    ushort* h2      = hagg + (size_t)NN * DH;            // [4][NN][16] bf16 (inv-scaled)

    // prep + bucket scatter + degree/inv
    k_prep<<<96, 256, 0, stream>>>(W1, W2, w1t, w2t, bcur);
    k_bscatter<<<NSB, 512, 0, stream>>>(src, dst, bcur, ebuf);
    k_deginv<<<NBK, 256, 0, stream>>>(ebuf, bcur, inv);

    // layer 1: h = slice8(inv .* (x @ W1)) ; hagg = slice8(relu(inv.*(sum+self)+b1))
    k_gemm_mfma<DH, false><<<(NN + 127) / 128, 256, 0, stream>>>(x, w1t, inv, h);
    k_aggl<8, true, false><<<NBK * 8, 256, 0, stream>>>(ebuf, bcur, h, inv, b1, hagg);

    // layer 2: h2 = slice4(inv .* (hagg @ W2)) ; out = inv.*(sum+self) + b2 (fp32)
    k_gemm_mfma<DO, true><<<(NN + 127) / 128, 256, 0, stream>>>(hagg, w2t, inv, h2);
    k_aggl<4, false, true><<<NBK * 4, 256, 0, stream>>>(ebuf, bcur, h2, inv, b2, out);
}

// Round 15
// 228.292 us; speedup vs baseline: 7.6758x; 7.6758x over previous
//
#include <hip/hip_runtime.h>

#define NN 100000
#define NE 1600000
#define DI 128
#define DH 128
#define DO 64
#define NBK 391           // buckets of 256 nodes (dst >> 8)
#define SLOT 5120         // per-bucket slot capacity (mean 4092 + 16 sigma)
#define PAD 16            // one counter per 64B line
#define EPB 8192          // edges per scatter block
#define NSB ((NE + EPB - 1) / EPB)  // 196

typedef unsigned int uint;
typedef unsigned short ushort;
typedef __bf16 bf16x8 __attribute__((ext_vector_type(8)));
typedef float f32x4 __attribute__((ext_vector_type(4)));

// ---- bf16 helpers (manual, RTNE) ----
__device__ __forceinline__ float bf_lo(uint u) { return __uint_as_float(u << 16); }
__device__ __forceinline__ float bf_hi(uint u) { return __uint_as_float(u & 0xffff0000u); }
__device__ __forceinline__ ushort f2bf(float f) {
    uint u = __float_as_uint(f);
    uint r = u + 0x7fffu + ((u >> 16) & 1u);
    return (ushort)(r >> 16);
}

// ---- prep: bucket cursor init + both weight transposes (bf16) ----
__global__ void k_prep(const float* __restrict__ W1, const float* __restrict__ W2,
                       ushort* __restrict__ w1t, ushort* __restrict__ w2t,
                       int* __restrict__ bcur) {
    int t = blockIdx.x * 256 + threadIdx.x;
    if (t < NBK) bcur[t * PAD] = t * SLOT;
    if (t < 128 * 128) {
        int c = t >> 7, k = t & 127;
        w1t[t] = f2bf(W1[k * 128 + c]);
    } else if (t < 128 * 128 + 64 * 128) {
        int u = t - 128 * 128;
        int c = u >> 7, k = u & 127;
        w2t[u] = f2bf(W2[k * 64 + c]);
    }
}

// ---- staged bucket scatter: LDS counting sort per 8192-edge block ----
__global__ __launch_bounds__(512) void k_bscatter(const int* __restrict__ src,
                                                  const int* __restrict__ dst,
                                                  int* __restrict__ bcur,
                                                  uint* __restrict__ ebuf) {
    __shared__ uint stage[EPB];        // 32 KB
    __shared__ ushort bktid[EPB];      // 16 KB
    __shared__ int lcnt[NBK];
    __shared__ int loff[NBK];
    __shared__ int gbase[NBK];
    __shared__ int s[512];
    int t = threadIdx.x;
    int e0 = blockIdx.x * EPB;
    int n = min(EPB, NE - e0);
    for (int i = t; i < NBK; i += 512) lcnt[i] = 0;
    __syncthreads();
    for (int i = t; i < n; i += 512)
        atomicAdd(&lcnt[dst[e0 + i] >> 8], 1);
    __syncthreads();
    int myc = (t < NBK) ? lcnt[t] : 0;
    s[t] = myc;
    __syncthreads();
    for (int d = 1; d < 512; d <<= 1) {
        int a = (t >= d) ? s[t - d] : 0;
        __syncthreads();
        s[t] += a;
        __syncthreads();
    }
    if (t < NBK) {
        loff[t] = s[t] - myc;
        gbase[t] = atomicAdd(&bcur[t * PAD], myc);
        lcnt[t] = s[t] - myc;
    }
    __syncthreads();
    for (int i = t; i < n; i += 512) {
        int d = dst[e0 + i];
        int sv = src[e0 + i];
        int b = d >> 8;
        int p = atomicAdd(&lcnt[b], 1);
        stage[p] = ((uint)sv << 8) | (uint)(d & 255);
        bktid[p] = (ushort)b;
    }
    __syncthreads();
    for (int j = t; j < n; j += 512) {
        int b = bktid[j];
        ebuf[gbase[b] + (j - loff[b])] = stage[j];
    }
}

// ---- per-bucket (256 nodes) hist + scan + fill; emits offdeg, inv, csr ----
__global__ __launch_bounds__(256) void k_bfill(const uint* __restrict__ ebuf,
                                               const int* __restrict__ bcur,
                                               uint2* __restrict__ offdeg,
                                               float* __restrict__ inv,
                                               int* __restrict__ csr_src) {
    __shared__ int cnt[256];
    __shared__ int s[256];
    __shared__ int cur[256];
    int b = blockIdx.x, t = threadIdx.x;
    int ebeg = b * SLOT;
    int eend = bcur[b * PAD];
    cnt[t] = 0;
    __syncthreads();
    for (int e = ebeg + t; e < eend; e += 256)
        atomicAdd(&cnt[ebuf[e] & 255], 1);
    __syncthreads();
    int v = cnt[t];
    s[t] = v;
    __syncthreads();
    for (int d = 1; d < 256; d <<= 1) {
        int a = (t >= d) ? s[t - d] : 0;
        __syncthreads();
        s[t] += a;
        __syncthreads();
    }
    int beg = ebeg + s[t] - v;
    int node = b * 256 + t;
    if (node < NN) {
        offdeg[node] = make_uint2((uint)beg, (uint)v);
        inv[node] = rsqrtf((float)v + 1.0f);
    }
    cur[t] = beg;
    __syncthreads();
    for (int e = ebeg + t; e < eend; e += 256) {
        uint ed = ebuf[e];
        int p = atomicAdd(&cur[ed & 255], 1);
        csr_src[p] = (int)(ed >> 8);
    }
}

// ---------------- MFMA GEMM: one wave = 32 rows x N cols, K=128 ----------------
// epilogue scales row r by inv[r]:  out[r] = bf16(inv[r] * (A@W)[r]), row-major out
template <int N, bool ABF16>
__global__ __launch_bounds__(256) void k_gemm_mfma(const void* __restrict__ Ap,
                                                   const ushort* __restrict__ Wt,
                                                   const float* __restrict__ inv,
                                                   ushort* __restrict__ out) {
    int wid = threadIdx.x >> 6;
    int lane = threadIdx.x & 63;
    int r0 = (blockIdx.x * 4 + wid) * 32;
    if (r0 >= NN) return;
    int rlo = lane & 15, khi = lane >> 4;  // khi in 0..3

    constexpr int CT = N / 16;  // 8 (N=128) or 4 (N=64)
    f32x4 acc[2][CT] = {};

#pragma unroll
    for (int ks = 0; ks < 4; ++ks) {
        bf16x8 bf[CT];
#pragma unroll
        for (int ct = 0; ct < CT; ++ct)
            bf[ct] = *(const bf16x8*)(Wt + (ct * 16 + rlo) * 128 + ks * 32 + khi * 8);
#pragma unroll
        for (int rt = 0; rt < 2; ++rt) {
            int row = r0 + rt * 16 + rlo;
            bf16x8 af;
            if (ABF16) {
                af = *(const bf16x8*)((const ushort*)Ap + (size_t)row * 128 + ks * 32 + khi * 8);
            } else {
                const float* pa = (const float*)Ap + (size_t)row * 128 + ks * 32 + khi * 8;
                float4 f0 = *(const float4*)pa;
                float4 f1 = *(const float4*)(pa + 4);
                af[0] = (__bf16)f0.x; af[1] = (__bf16)f0.y;
                af[2] = (__bf16)f0.z; af[3] = (__bf16)f0.w;
                af[4] = (__bf16)f1.x; af[5] = (__bf16)f1.y;
                af[6] = (__bf16)f1.z; af[7] = (__bf16)f1.w;
            }
#pragma unroll
            for (int ct = 0; ct < CT; ++ct)
                acc[rt][ct] = __builtin_amdgcn_mfma_f32_16x16x32_bf16(af, bf[ct], acc[rt][ct], 0, 0, 0);
        }
    }
#pragma unroll
    for (int rt = 0; rt < 2; ++rt) {
        int rowb = r0 + rt * 16 + 4 * khi;
#pragma unroll
        for (int b = 0; b < 4; ++b) {
            float sc = inv[rowb + b];
#pragma unroll
            for (int ct = 0; ct < CT; ++ct)
                out[(size_t)(rowb + b) * N + ct * 16 + rlo] = f2bf(acc[rt][ct][b] * sc);
        }
    }
}

// ---------------- gather aggregation, D=128 (one wave = one node) ----------------
// tab[s] = bf16(inv[s]*h[s]); out[d] = bf16(relu(inv[d]*(sum tab[src] + tab[d]) + bias))
template <bool RELU>
__global__ void k_agg128(const uint2* __restrict__ offdeg, const int* __restrict__ csr,
                         const ushort* __restrict__ tab, const float* __restrict__ inv,
                         const float* __restrict__ bias, ushort* __restrict__ outb) {
    int wid = threadIdx.x >> 6, lane = threadIdx.x & 63;
    int node = blockIdx.x * (blockDim.x >> 6) + wid;
    if (node >= NN) return;
    uint2 od = offdeg[node];
    int beg = (int)od.x, end = beg + (int)od.y;
    const uint* t32 = (const uint*)tab;  // [NN][64] packed bf16 pairs
    float a0 = 0.f, a1 = 0.f;
    int e = beg;
    for (; e + 3 < end; e += 4) {
        int s0 = csr[e], s1 = csr[e + 1], s2 = csr[e + 2], s3 = csr[e + 3];
        uint u0 = t32[(size_t)s0 * 64 + lane];
        uint u1 = t32[(size_t)s1 * 64 + lane];
        uint u2 = t32[(size_t)s2 * 64 + lane];
        uint u3 = t32[(size_t)s3 * 64 + lane];
        a0 += bf_lo(u0); a1 += bf_hi(u0);
        a0 += bf_lo(u1); a1 += bf_hi(u1);
        a0 += bf_lo(u2); a1 += bf_hi(u2);
        a0 += bf_lo(u3); a1 += bf_hi(u3);
    }
    for (; e < end; ++e) {
        int s = csr[e];
        uint u = t32[(size_t)s * 64 + lane];
        a0 += bf_lo(u); a1 += bf_hi(u);
    }
    float invd = inv[node];
    uint us = t32[(size_t)node * 64 + lane];
    float2 b = *(const float2*)(bias + lane * 2);
    float r0 = fmaf(invd, a0 + bf_lo(us), b.x);
    float r1 = fmaf(invd, a1 + bf_hi(us), b.y);
    if (RELU) { r0 = fmaxf(r0, 0.f); r1 = fmaxf(r1, 0.f); }
    uint packed = (uint)f2bf(r0) | ((uint)f2bf(r1) << 16);
    *(uint*)(outb + (size_t)node * 128 + lane * 2) = packed;
}

// ---------------- gather aggregation, D=64: TWO nodes per wave ----------------
// half = lane>>5 selects node; 32 lanes x uint (2 feats) cover the 64-feat row.
// Same bytes per gather instruction as before but 2x edges per instruction stream.
__global__ void k_agg64(const uint2* __restrict__ offdeg, const int* __restrict__ csr,
                        const ushort* __restrict__ tab, const float* __restrict__ inv,
                        const float* __restrict__ bias, float* __restrict__ out) {
    int wid = threadIdx.x >> 6, lane = threadIdx.x & 63;
    int half = lane >> 5, u = lane & 31;
    int node = (blockIdx.x * (blockDim.x >> 6) + wid) * 2 + half;
    if (node >= NN) return;
    uint2 od = offdeg[node];
    int beg = (int)od.x, end = beg + (int)od.y;
    const uint* t32 = (const uint*)tab;  // [NN][32] packed bf16 pairs
    float a0 = 0.f, a1 = 0.f;
    int e = beg;
    for (; e + 3 < end; e += 4) {
        int s0 = csr[e], s1 = csr[e + 1], s2 = csr[e + 2], s3 = csr[e + 3];
        uint u0 = t32[(size_t)s0 * 32 + u];
        uint u1 = t32[(size_t)s1 * 32 + u];
        uint u2 = t32[(size_t)s2 * 32 + u];
        uint u3 = t32[(size_t)s3 * 32 + u];
        a0 += bf_lo(u0); a1 += bf_hi(u0);
        a0 += bf_lo(u1); a1 += bf_hi(u1);
        a0 += bf_lo(u2); a1 += bf_hi(u2);
        a0 += bf_lo(u3); a1 += bf_hi(u3);
    }
    for (; e < end; ++e) {
        int s = csr[e];
        uint uu = t32[(size_t)s * 32 + u];
        a0 += bf_lo(uu); a1 += bf_hi(uu);
    }
    float invd = inv[node];
    uint us = t32[(size_t)node * 32 + u];
    float2 bb = *(const float2*)(bias + u * 2);
    float r0 = fmaf(invd, a0 + bf_lo(us), bb.x);
    float r1 = fmaf(invd, a1 + bf_hi(us), bb.y);
    *(float2*)(out + (size_t)node * 64 + u * 2) = make_float2(r0, r1);
}

extern "C" void kernel_launch(void* const* d_in, const int* in_sizes, int n_in,
                              void* d_out, int out_size, void* d_ws, size_t ws_size,
                              hipStream_t stream) {
    const float* x  = (const float*)d_in[0];
    const int* ei   = (const int*)d_in[1];
    const int* src  = ei;        // edge_index[0]
    const int* dst  = ei + NE;   // edge_index[1]
    const float* W1 = (const float*)d_in[2];
    const float* b1 = (const float*)d_in[3];
    const float* W2 = (const float*)d_in[4];
    const float* b2 = (const float*)d_in[5];
    float* out = (float*)d_out;

    // workspace layout (16B alignment maintained)
    uint2*  offdeg  = (uint2*)d_ws;                      // NN uint2
    float*  inv     = (float*)(offdeg + NN);             // 100004 floats
    int*    bcur    = (int*)(inv + 100004);              // NBK*16 ints (padded)
    int*    csr_src = bcur + NBK * PAD;                  // NBK*SLOT ints (slotted)
    ushort* w1t     = (ushort*)(csr_src + NBK * SLOT);   // 128*128 bf16
    ushort* w2t     = w1t + 128 * 128;                   // 64*128 bf16
    ushort* h       = w2t + 64 * 128;                    // NN*128 bf16 (inv-scaled)
    ushort* hagg    = h + (size_t)NN * DH;               // NN*128 bf16
    ushort* h2      = hagg + (size_t)NN * DH;            // NN*64 bf16 (inv-scaled)
    uint*   ebuf    = (uint*)h2;                         // NBK*SLOT uint, aliases h2 (dead until gemm2)

    // prep (bcur init + weight transposes), then CSR build
    k_prep<<<96, 256, 0, stream>>>(W1, W2, w1t, w2t, bcur);
    k_bscatter<<<NSB, 512, 0, stream>>>(src, dst, bcur, ebuf);
    k_bfill<<<NBK, 256, 0, stream>>>(ebuf, bcur, offdeg, inv, csr_src);

    // layer 1: h = bf16(inv .* (x @ W1)) ; hagg = bf16(relu(inv.*(sum tab + self) + b1))
    k_gemm_mfma<DH, false><<<(NN + 127) / 128, 256, 0, stream>>>(x, w1t, inv, h);
    k_agg128<true><<<NN / 4, 256, 0, stream>>>(offdeg, csr_src, h, inv, b1, hagg);

    // layer 2: h2 = bf16(inv .* (hagg @ W2)) ; out = inv.*(sum tab2 + self) + b2 (fp32)
    k_gemm_mfma<DO, true><<<(NN + 127) / 128, 256, 0, stream>>>(hagg, w2t, inv, h2);
    k_agg64<<<(NN + 7) / 8, 256, 0, stream>>>(offdeg, csr_src, h2, inv, b2, out);
}

// Round 16
// 227.762 us; speedup vs baseline: 7.6936x; 1.0023x over previous
//
#include <hip/hip_runtime.h>

#define NN 100000
#define NE 1600000
#define DI 128
#define DH 128
#define DO 64
#define NBK 391           // buckets of 256 nodes (dst >> 8)
#define SLOT 5120         // per-bucket slot capacity (mean 4092 + 16 sigma)
#define PAD 16            // one counter per 64B line
#define EPB 8192          // edges per scatter block
#define NSB ((NE + EPB - 1) / EPB)  // 196

typedef unsigned int uint;
typedef unsigned short ushort;
typedef __bf16 bf16x8 __attribute__((ext_vector_type(8)));
typedef float f32x4 __attribute__((ext_vector_type(4)));

// ---- bf16 helpers (manual, RTNE) ----
__device__ __forceinline__ float bf_lo(uint u) { return __uint_as_float(u << 16); }
__device__ __forceinline__ float bf_hi(uint u) { return __uint_as_float(u & 0xffff0000u); }
__device__ __forceinline__ ushort f2bf(float f) {
    uint u = __float_as_uint(f);
    uint r = u + 0x7fffu + ((u >> 16) & 1u);
    return (ushort)(r >> 16);
}

// ---- staged bucket scatter: LDS counting sort per 8192-edge block ----
// bcur is memset-zeroed; global region base = b*SLOT + atomic count.
__global__ __launch_bounds__(512) void k_bscatter(const int* __restrict__ src,
                                                  const int* __restrict__ dst,
                                                  int* __restrict__ bcur,
                                                  uint* __restrict__ ebuf) {
    __shared__ uint stage[EPB];        // 32 KB
    __shared__ ushort bktid[EPB];      // 16 KB
    __shared__ int lcnt[NBK];
    __shared__ int loff[NBK];
    __shared__ int gbase[NBK];
    __shared__ int s[512];
    int t = threadIdx.x;
    int e0 = blockIdx.x * EPB;
    int n = min(EPB, NE - e0);
    for (int i = t; i < NBK; i += 512) lcnt[i] = 0;
    __syncthreads();
    for (int i = t; i < n; i += 512)
        atomicAdd(&lcnt[dst[e0 + i] >> 8], 1);
    __syncthreads();
    int myc = (t < NBK) ? lcnt[t] : 0;
    s[t] = myc;
    __syncthreads();
    for (int d = 1; d < 512; d <<= 1) {
        int a = (t >= d) ? s[t - d] : 0;
        __syncthreads();
        s[t] += a;
        __syncthreads();
    }
    if (t < NBK) {
        loff[t] = s[t] - myc;
        gbase[t] = t * SLOT + atomicAdd(&bcur[t * PAD], myc);
        lcnt[t] = s[t] - myc;
    }
    __syncthreads();
    for (int i = t; i < n; i += 512) {
        int d = dst[e0 + i];
        int sv = src[e0 + i];
        int b = d >> 8;
        int p = atomicAdd(&lcnt[b], 1);
        stage[p] = ((uint)sv << 8) | (uint)(d & 255);
        bktid[p] = (ushort)b;
    }
    __syncthreads();
    for (int j = t; j < n; j += 512) {
        int b = bktid[j];
        ebuf[gbase[b] + (j - loff[b])] = stage[j];
    }
}

// ---- per-bucket (256 nodes) hist + scan + fill; emits offdeg, inv, csr ----
// blocks 0..95 additionally transpose W1/W2 to bf16 (256 elems each).
__global__ __launch_bounds__(256) void k_bfill(const uint* __restrict__ ebuf,
                                               const int* __restrict__ bcur,
                                               uint2* __restrict__ offdeg,
                                               float* __restrict__ inv,
                                               int* __restrict__ csr_src,
                                               const float* __restrict__ W1,
                                               const float* __restrict__ W2,
                                               ushort* __restrict__ w1t,
                                               ushort* __restrict__ w2t) {
    __shared__ int cnt[256];
    __shared__ int s[256];
    __shared__ int cur[256];
    int b = blockIdx.x, t = threadIdx.x;
    // fused weight transpose (independent of bucket work)
    {
        int g = b * 256 + t;
        if (g < 128 * 128) {
            int c = g >> 7, k = g & 127;
            w1t[g] = f2bf(W1[k * 128 + c]);
        } else if (g < 128 * 128 + 64 * 128) {
            int u = g - 128 * 128;
            int c = u >> 7, k = u & 127;
            w2t[u] = f2bf(W2[k * 64 + c]);
        }
    }
    int ebeg = b * SLOT;
    int eend = ebeg + bcur[b * PAD];
    cnt[t] = 0;
    __syncthreads();
    for (int e = ebeg + t; e < eend; e += 256)
        atomicAdd(&cnt[ebuf[e] & 255], 1);
    __syncthreads();
    int v = cnt[t];
    s[t] = v;
    __syncthreads();
    for (int d = 1; d < 256; d <<= 1) {
        int a = (t >= d) ? s[t - d] : 0;
        __syncthreads();
        s[t] += a;
        __syncthreads();
    }
    int beg = ebeg + s[t] - v;
    int node = b * 256 + t;
    if (node < NN) {
        offdeg[node] = make_uint2((uint)beg, (uint)v);
        inv[node] = rsqrtf((float)v + 1.0f);
    }
    cur[t] = beg;
    __syncthreads();
    for (int e = ebeg + t; e < eend; e += 256) {
        uint ed = ebuf[e];
        int p = atomicAdd(&cur[ed & 255], 1);
        csr_src[p] = (int)(ed >> 8);
    }
}

// ---------------- MFMA GEMM: one wave = 32 rows x N cols, K=128 ----------------
// epilogue scales row r by inv[r]:  out[r] = bf16(inv[r] * (A@W)[r]), row-major out
template <int N, bool ABF16>
__global__ __launch_bounds__(256) void k_gemm_mfma(const void* __restrict__ Ap,
                                                   const ushort* __restrict__ Wt,
                                                   const float* __restrict__ inv,
                                                   ushort* __restrict__ out) {
    int wid = threadIdx.x >> 6;
    int lane = threadIdx.x & 63;
    int r0 = (blockIdx.x * 4 + wid) * 32;
    if (r0 >= NN) return;
    int rlo = lane & 15, khi = lane >> 4;  // khi in 0..3

    constexpr int CT = N / 16;  // 8 (N=128) or 4 (N=64)
    f32x4 acc[2][CT] = {};

#pragma unroll
    for (int ks = 0; ks < 4; ++ks) {
        bf16x8 bf[CT];
#pragma unroll
        for (int ct = 0; ct < CT; ++ct)
            bf[ct] = *(const bf16x8*)(Wt + (ct * 16 + rlo) * 128 + ks * 32 + khi * 8);
#pragma unroll
        for (int rt = 0; rt < 2; ++rt) {
            int row = r0 + rt * 16 + rlo;
            bf16x8 af;
            if (ABF16) {
                af = *(const bf16x8*)((const ushort*)Ap + (size_t)row * 128 + ks * 32 + khi * 8);
            } else {
                const float* pa = (const float*)Ap + (size_t)row * 128 + ks * 32 + khi * 8;
                float4 f0 = *(const float4*)pa;
                float4 f1 = *(const float4*)(pa + 4);
                af[0] = (__bf16)f0.x; af[1] = (__bf16)f0.y;
                af[2] = (__bf16)f0.z; af[3] = (__bf16)f0.w;
                af[4] = (__bf16)f1.x; af[5] = (__bf16)f1.y;
                af[6] = (__bf16)f1.z; af[7] = (__bf16)f1.w;
            }
#pragma unroll
            for (int ct = 0; ct < CT; ++ct)
                acc[rt][ct] = __builtin_amdgcn_mfma_f32_16x16x32_bf16(af, bf[ct], acc[rt][ct], 0, 0, 0);
        }
    }
#pragma unroll
    for (int rt = 0; rt < 2; ++rt) {
        int rowb = r0 + rt * 16 + 4 * khi;
#pragma unroll
        for (int b = 0; b < 4; ++b) {
            float sc = inv[rowb + b];
#pragma unroll
            for (int ct = 0; ct < CT; ++ct)
                out[(size_t)(rowb + b) * N + ct * 16 + rlo] = f2bf(acc[rt][ct][b] * sc);
        }
    }
}

// ---------------- gather aggregation, D=128 (one wave = one node) ----------------
// tab[s] = bf16(inv[s]*h[s]); out[d] = bf16(relu(inv[d]*(sum tab[src] + tab[d]) + bias))
template <bool RELU>
__global__ void k_agg128(const uint2* __restrict__ offdeg, const int* __restrict__ csr,
                         const ushort* __restrict__ tab, const float* __restrict__ inv,
                         const float* __restrict__ bias, ushort* __restrict__ outb) {
    int wid = threadIdx.x >> 6, lane = threadIdx.x & 63;
    int node = blockIdx.x * (blockDim.x >> 6) + wid;
    if (node >= NN) return;
    uint2 od = offdeg[node];
    int beg = (int)od.x, end = beg + (int)od.y;
    const uint* t32 = (const uint*)tab;  // [NN][64] packed bf16 pairs
    float a0 = 0.f, a1 = 0.f;
    int e = beg;
    for (; e + 3 < end; e += 4) {
        int s0 = csr[e], s1 = csr[e + 1], s2 = csr[e + 2], s3 = csr[e + 3];
        uint u0 = t32[(size_t)s0 * 64 + lane];
        uint u1 = t32[(size_t)s1 * 64 + lane];
        uint u2 = t32[(size_t)s2 * 64 + lane];
        uint u3 = t32[(size_t)s3 * 64 + lane];
        a0 += bf_lo(u0); a1 += bf_hi(u0);
        a0 += bf_lo(u1); a1 += bf_hi(u1);
        a0 += bf_lo(u2); a1 += bf_hi(u2);
        a0 += bf_lo(u3); a1 += bf_hi(u3);
    }
    for (; e < end; ++e) {
        int s = csr[e];
        uint u = t32[(size_t)s * 64 + lane];
        a0 += bf_lo(u); a1 += bf_hi(u);
    }
    float invd = inv[node];
    uint us = t32[(size_t)node * 64 + lane];
    float2 b = *(const float2*)(bias + lane * 2);
    float r0 = fmaf(invd, a0 + bf_lo(us), b.x);
    float r1 = fmaf(invd, a1 + bf_hi(us), b.y);
    if (RELU) { r0 = fmaxf(r0, 0.f); r1 = fmaxf(r1, 0.f); }
    uint packed = (uint)f2bf(r0) | ((uint)f2bf(r1) << 16);
    *(uint*)(outb + (size_t)node * 128 + lane * 2) = packed;
}

// ---------------- gather aggregation, D=64: TWO nodes per wave ----------------
__global__ void k_agg64(const uint2* __restrict__ offdeg, const int* __restrict__ csr,
                        const ushort* __restrict__ tab, const float* __restrict__ inv,
                        const float* __restrict__ bias, float* __restrict__ out) {
    int wid = threadIdx.x >> 6, lane = threadIdx.x & 63;
    int half = lane >> 5, u = lane & 31;
    int node = (blockIdx.x * (blockDim.x >> 6) + wid) * 2 + half;
    if (node >= NN) return;
    uint2 od = offdeg[node];
    int beg = (int)od.x, end = beg + (int)od.y;
    const uint* t32 = (const uint*)tab;  // [NN][32] packed bf16 pairs
    float a0 = 0.f, a1 = 0.f;
    int e = beg;
    for (; e + 3 < end; e += 4) {
        int s0 = csr[e], s1 = csr[e + 1], s2 = csr[e + 2], s3 = csr[e + 3];
        uint u0 = t32[(size_t)s0 * 32 + u];
        uint u1 = t32[(size_t)s1 * 32 + u];
        uint u2 = t32[(size_t)s2 * 32 + u];
        uint u3 = t32[(size_t)s3 * 32 + u];
        a0 += bf_lo(u0); a1 += bf_hi(u0);
        a0 += bf_lo(u1); a1 += bf_hi(u1);
        a0 += bf_lo(u2); a1 += bf_hi(u2);
        a0 += bf_lo(u3); a1 += bf_hi(u3);
    }
    for (; e < end; ++e) {
        int s = csr[e];
        uint uu = t32[(size_t)s * 32 + u];
        a0 += bf_lo(uu); a1 += bf_hi(uu);
    }
    float invd = inv[node];
    uint us = t32[(size_t)node * 32 + u];
    float2 bb = *(const float2*)(bias + u * 2);
    float r0 = fmaf(invd, a0 + bf_lo(us), bb.x);
    float r1 = fmaf(invd, a1 + bf_hi(us), bb.y);
    *(float2*)(out + (size_t)node * 64 + u * 2) = make_float2(r0, r1);
}

extern "C" void kernel_launch(void* const* d_in, const int* in_sizes, int n_in,
                              void* d_out, int out_size, void* d_ws, size_t ws_size,
                              hipStream_t stream) {
    const float* x  = (const float*)d_in[0];
    const int* ei   = (const int*)d_in[1];
    const int* src  = ei;        // edge_index[0]
    const int* dst  = ei + NE;   // edge_index[1]
    const float* W1 = (const float*)d_in[2];
    const float* b1 = (const float*)d_in[3];
    const float* W2 = (const float*)d_in[4];
    const float* b2 = (const float*)d_in[5];
    float* out = (float*)d_out;

    // workspace layout (16B alignment maintained)
    uint2*  offdeg  = (uint2*)d_ws;                      // NN uint2
    float*  inv     = (float*)(offdeg + NN);             // 100004 floats
    int*    bcur    = (int*)(inv + 100004);              // NBK*16 ints (padded)
    int*    csr_src = bcur + NBK * PAD;                  // NBK*SLOT ints (slotted)
    ushort* w1t     = (ushort*)(csr_src + NBK * SLOT);   // 128*128 bf16
    ushort* w2t     = w1t + 128 * 128;                   // 64*128 bf16
    ushort* h       = w2t + 64 * 128;                    // NN*128 bf16 (inv-scaled)
    ushort* hagg    = h + (size_t)NN * DH;               // NN*128 bf16
    ushort* h2      = hagg + (size_t)NN * DH;            // NN*64 bf16 (inv-scaled)
    uint*   ebuf    = (uint*)h2;                         // NBK*SLOT uint, aliases h2 (dead until gemm2)

    // CSR build: zero cursors (async memset), scatter, fill (+fused W transposes)
    hipMemsetAsync(bcur, 0, (size_t)NBK * PAD * sizeof(int), stream);
    k_bscatter<<<NSB, 512, 0, stream>>>(src, dst, bcur, ebuf);
    k_bfill<<<NBK, 256, 0, stream>>>(ebuf, bcur, offdeg, inv, csr_src, W1, W2, w1t, w2t);

    // layer 1: h = bf16(inv .* (x @ W1)) ; hagg = bf16(relu(inv.*(sum tab + self) + b1))
    k_gemm_mfma<DH, false><<<(NN + 127) / 128, 256, 0, stream>>>(x, w1t, inv, h);
    k_agg128<true><<<NN / 4, 256, 0, stream>>>(offdeg, csr_src, h, inv, b1, hagg);

    // layer 2: h2 = bf16(inv .* (hagg @ W2)) ; out = inv.*(sum tab2 + self) + b2 (fp32)
    k_gemm_mfma<DO, true><<<(NN + 127) / 128, 256, 0, stream>>>(hagg, w2t, inv, h2);
    k_agg64<<<(NN + 7) / 8, 256, 0, stream>>>(offdeg, csr_src, h2, inv, b2, out);
}